// Round 2
// baseline (470.471 us; speedup 1.0000x reference)
//
#include <hip/hip_runtime.h>

#define B_ 4
#define C_ 128
#define L_ 128
#define N_ 64
#define KPAD 7

// ---------------- Kernel A: SSM kernels k0,k1 ----------------
// kbuf floats: [k0_re 16384][k0_im 16384][k1_re 16384][k1_im 16384]
__global__ __launch_bounds__(256) void compute_k_kernel(
    const float* __restrict__ logA, const float* __restrict__ Aim,
    const float* __restrict__ Bre, const float* __restrict__ Bim,
    const float* __restrict__ Cre, const float* __restrict__ Cim,
    const float* __restrict__ logdt, float* __restrict__ kbuf)
{
    int idx = blockIdx.x * 256 + threadIdx.x;   // axis*16384 + c*128 + t
    int axis = idx >> 14;
    int c = (idx >> 7) & 127;
    int t = idx & 127;
    float dt = expf(logdt[axis * C_ + c]);
    float tf = (float)t;
    const float* lA = logA + (axis * C_ + c) * N_;
    const float* br = Bre + (axis * C_ + c) * N_;
    const float* bi = Bim + (axis * C_ + c) * N_;
    const float* cr = Cre + (axis * C_ + c) * N_;
    const float* ci = Cim + (axis * C_ + c) * N_;
    const float* ai = Aim + axis * N_;
    float kr = 0.f, ki = 0.f;
    for (int n = 0; n < N_; ++n) {
        float zre = -expf(lA[n]) * dt;
        float zim = ai[n] * dt;
        float mag = expf(zre * tf);
        float s, co;
        sincosf(zim * tf, &s, &co);
        float wr = mag * co, wi = mag * s;
        float cbr = cr[n] * br[n] - ci[n] * bi[n];
        float cbi = cr[n] * bi[n] + ci[n] * br[n];
        kr += cbr * wr - cbi * wi;
        ki += cbr * wi + cbi * wr;
    }
    kbuf[axis * 32768 + c * L_ + t] = kr;
    kbuf[axis * 32768 + 16384 + c * L_ + t] = ki;
}

// ---------------- Kernel B: fused 2D causal conv per (b,c) image ----------------
// z(x,y) = sum_{j<=y} k1[y-j] * ( sum_{a<=x} k0[x-a] * u(a,j) )
// Whole image in LDS. conv_x writes transposed -> conv_y also reads rows.
__global__ __launch_bounds__(512) void conv2d_kernel(
    const float* __restrict__ u_re, const float* __restrict__ u_im,
    const float* __restrict__ kbuf, float* __restrict__ z_re, float* __restrict__ z_im)
{
    __shared__ __align__(16) float br[128][128];
    __shared__ __align__(16) float bi[128][128];
    __shared__ float kx0r[136], kx0i[136], kx1r[136], kx1i[136];
    int bc = blockIdx.x;
    int c = bc & 127;
    int tid = threadIdx.x;
    if (tid < 136) {
        int t = tid - KPAD;
        bool v = (t >= 0 && t < 128);
        kx0r[tid] = v ? kbuf[c * 128 + t] : 0.f;
        kx0i[tid] = v ? kbuf[16384 + c * 128 + t] : 0.f;
        kx1r[tid] = v ? kbuf[32768 + c * 128 + t] : 0.f;
        kx1i[tid] = v ? kbuf[49152 + c * 128 + t] : 0.f;
    }
    size_t gbase = (size_t)bc * 16384;
    {
        int r = tid >> 2, q = tid & 3;
        const float4* gr = (const float4*)(u_re + gbase + r * 128 + q * 32);
        const float4* gi = (const float4*)(u_im + gbase + r * 128 + q * 32);
        float4* lr = (float4*)&br[r][q * 32];
        float4* li = (float4*)&bi[r][q * 32];
#pragma unroll
        for (int m = 0; m < 8; ++m) { lr[m] = gr[m]; li[m] = gi[m]; }
    }
    __syncthreads();

    // ---- conv_x: z1(x,y) = sum_a k0[x-a]*u(a,y). Thread: x0..x0+3, y in {yb+0..3, 64+yb..+3}
    int xq = tid >> 4;              // 0..31
    int yq = tid & 15;              // 0..15
    int x0 = xq << 2;
    int yb = yq << 2;
    float ar[4][8], ai_[4][8];
#pragma unroll
    for (int k = 0; k < 4; ++k)
#pragma unroll
        for (int m = 0; m < 8; ++m) { ar[k][m] = 0.f; ai_[k][m] = 0.f; }
    for (int a = 0; a < 128; ++a) {
        float4 u0 = *(const float4*)&br[a][yb];
        float4 u1 = *(const float4*)&br[a][64 + yb];
        float4 v0 = *(const float4*)&bi[a][yb];
        float4 v1 = *(const float4*)&bi[a][64 + yb];
        float ur[8] = {u0.x, u0.y, u0.z, u0.w, u1.x, u1.y, u1.z, u1.w};
        float ui[8] = {v0.x, v0.y, v0.z, v0.w, v1.x, v1.y, v1.z, v1.w};
        int j = x0 - a + KPAD; j = j < 0 ? 0 : j;
#pragma unroll
        for (int k = 0; k < 4; ++k) {
            float kr = kx0r[j + k], ki = kx0i[j + k];
#pragma unroll
            for (int m = 0; m < 8; ++m) {
                ar[k][m] += kr * ur[m] - ki * ui[m];
                ai_[k][m] += kr * ui[m] + ki * ur[m];
            }
        }
    }
    __syncthreads();
    // write z1 transposed: br[y][x] = z1(x,y)
#pragma unroll
    for (int m = 0; m < 8; ++m) {
        int y = (m < 4) ? (yb + m) : (64 + yb + m - 4);
        *(float4*)&br[y][x0] = make_float4(ar[0][m], ar[1][m], ar[2][m], ar[3][m]);
        *(float4*)&bi[y][x0] = make_float4(ai_[0][m], ai_[1][m], ai_[2][m], ai_[3][m]);
    }
    __syncthreads();

    // ---- conv_y: z2(x,y) = sum_j k1[y-j]*z1(x,j) = sum_j k1[y-j]*br[j][x]
    int xq2 = tid & 15;             // 0..15
    int yq2 = tid >> 4;             // 0..31
    int xb = xq2 << 2;
    int y0 = yq2 << 2;
    float cr[4][8], ci_[4][8];
#pragma unroll
    for (int k = 0; k < 4; ++k)
#pragma unroll
        for (int m = 0; m < 8; ++m) { cr[k][m] = 0.f; ci_[k][m] = 0.f; }
    for (int j = 0; j < 128; ++j) {
        float4 z0 = *(const float4*)&br[j][xb];
        float4 z1v = *(const float4*)&br[j][64 + xb];
        float4 w0 = *(const float4*)&bi[j][xb];
        float4 w1 = *(const float4*)&bi[j][64 + xb];
        float zr[8] = {z0.x, z0.y, z0.z, z0.w, z1v.x, z1v.y, z1v.z, z1v.w};
        float zi[8] = {w0.x, w0.y, w0.z, w0.w, w1.x, w1.y, w1.z, w1.w};
        int j2 = y0 - j + KPAD; j2 = j2 < 0 ? 0 : j2;
#pragma unroll
        for (int k = 0; k < 4; ++k) {
            float kr = kx1r[j2 + k], ki = kx1i[j2 + k];
#pragma unroll
            for (int m = 0; m < 8; ++m) {
                cr[k][m] += kr * zr[m] - ki * zi[m];
                ci_[k][m] += kr * zi[m] + ki * zr[m];
            }
        }
    }
    __syncthreads();
    // write z2 back normal layout: br[x][y]
#pragma unroll
    for (int m = 0; m < 8; ++m) {
        int x = (m < 4) ? (xb + m) : (64 + xb + m - 4);
        *(float4*)&br[x][y0] = make_float4(cr[0][m], cr[1][m], cr[2][m], cr[3][m]);
        *(float4*)&bi[x][y0] = make_float4(ci_[0][m], ci_[1][m], ci_[2][m], ci_[3][m]);
    }
    __syncthreads();
    {
        int r = tid >> 2, q = tid & 3;
        float4* gr = (float4*)(z_re + gbase + r * 128 + q * 32);
        float4* gi = (float4*)(z_im + gbase + r * 128 + q * 32);
#pragma unroll
        for (int m = 0; m < 8; ++m) {
            gr[m] = *(float4*)&br[r][q * 32 + 4 * m];
            gi[m] = *(float4*)&bi[r][q * 32 + 4 * m];
        }
    }
}

// ---------------- Kernel C: channel mix, REAL output only, in-place on z_re ----------------
// out[b,d,s] = sum_c Wre[d,c]*zre[b,c,s] - Wim[d,c]*zim[b,c,s]
__global__ __launch_bounds__(256) void mix_kernel(
    float* __restrict__ z_re, const float* __restrict__ z_im,
    const float* __restrict__ Wre, const float* __restrict__ Wim)
{
    __shared__ __align__(16) float zr_s[32][128];
    __shared__ __align__(16) float zi_s[32][128];
    __shared__ __align__(16) float wr_s[32][132];
    __shared__ __align__(16) float wi_s[32][132];
    int bid = blockIdx.x;
    int b = bid >> 7;
    int s0 = (bid & 127) << 7;
    int tid = threadIdx.x;
    int sq = tid & 15;              // s-split {4sq+i, 64+4sq+i}
    int dq = tid >> 4;              // d-split {4dq+i, 64+4dq+i}
    float acc[8][8];
#pragma unroll
    for (int di = 0; di < 8; ++di)
#pragma unroll
        for (int si = 0; si < 8; ++si) acc[di][si] = 0.f;

    for (int c0 = 0; c0 < 128; c0 += 32) {
        __syncthreads();
#pragma unroll
        for (int it = 0; it < 4; ++it) {
            int idx4 = it * 256 + tid;
            int cc = idx4 >> 5, sR = (idx4 & 31) << 2;
            *(float4*)&zr_s[cc][sR] =
                *(const float4*)&z_re[(size_t)(b * 128 + c0 + cc) * 16384 + s0 + sR];
            *(float4*)&zi_s[cc][sR] =
                *(const float4*)&z_im[(size_t)(b * 128 + c0 + cc) * 16384 + s0 + sR];
        }
#pragma unroll
        for (int it = 0; it < 4; ++it) {
            int idx4 = it * 256 + tid;
            int d = idx4 >> 3, ccR = (idx4 & 7) << 2;
            float4 wr = *(const float4*)&Wre[d * 128 + c0 + ccR];
            float4 wi = *(const float4*)&Wim[d * 128 + c0 + ccR];
            wr_s[ccR + 0][d] = wr.x; wr_s[ccR + 1][d] = wr.y;
            wr_s[ccR + 2][d] = wr.z; wr_s[ccR + 3][d] = wr.w;
            wi_s[ccR + 0][d] = wi.x; wi_s[ccR + 1][d] = wi.y;
            wi_s[ccR + 2][d] = wi.z; wi_s[ccR + 3][d] = wi.w;
        }
        __syncthreads();
        for (int cc = 0; cc < 32; ++cc) {
            float4 a0 = *(const float4*)&wr_s[cc][4 * dq];
            float4 a1 = *(const float4*)&wr_s[cc][64 + 4 * dq];
            float4 b0 = *(const float4*)&wi_s[cc][4 * dq];
            float4 b1 = *(const float4*)&wi_s[cc][64 + 4 * dq];
            float4 c0v = *(const float4*)&zr_s[cc][4 * sq];
            float4 c1v = *(const float4*)&zr_s[cc][64 + 4 * sq];
            float4 d0v = *(const float4*)&zi_s[cc][4 * sq];
            float4 d1v = *(const float4*)&zi_s[cc][64 + 4 * sq];
            float wr[8] = {a0.x, a0.y, a0.z, a0.w, a1.x, a1.y, a1.z, a1.w};
            float wi[8] = {b0.x, b0.y, b0.z, b0.w, b1.x, b1.y, b1.z, b1.w};
            float zr[8] = {c0v.x, c0v.y, c0v.z, c0v.w, c1v.x, c1v.y, c1v.z, c1v.w};
            float zi[8] = {d0v.x, d0v.y, d0v.z, d0v.w, d1v.x, d1v.y, d1v.z, d1v.w};
#pragma unroll
            for (int di = 0; di < 8; ++di)
#pragma unroll
                for (int si = 0; si < 8; ++si)
                    acc[di][si] += wr[di] * zr[si] - wi[di] * zi[si];
        }
    }
    __syncthreads();
#pragma unroll
    for (int di = 0; di < 8; ++di) {
        int d = (di < 4) ? (4 * dq + di) : (64 + 4 * dq + di - 4);
        float* o = z_re + (size_t)(b * 128 + d) * 16384 + s0;
        *(float4*)&o[4 * sq] = make_float4(acc[di][0], acc[di][1], acc[di][2], acc[di][3]);
        *(float4*)&o[64 + 4 * sq] = make_float4(acc[di][4], acc[di][5], acc[di][6], acc[di][7]);
    }
}

extern "C" void kernel_launch(void* const* d_in, const int* in_sizes, int n_in,
                              void* d_out, int out_size, void* d_ws, size_t ws_size,
                              hipStream_t stream) {
    const float* u_re  = (const float*)d_in[0];
    const float* u_im  = (const float*)d_in[1];
    const float* logA  = (const float*)d_in[2];
    const float* Aim   = (const float*)d_in[3];
    const float* Bre   = (const float*)d_in[4];
    const float* Bim   = (const float*)d_in[5];
    const float* Cre   = (const float*)d_in[6];
    const float* Cim   = (const float*)d_in[7];
    const float* logdt = (const float*)d_in[8];
    const float* Wre   = (const float*)d_in[9];
    const float* Wim   = (const float*)d_in[10];
    float* kbuf = (float*)d_ws;                       // 256 KB
    float* z_im = (float*)d_ws + 65536;               // 33.5 MB
    float* z_re = (float*)d_out;                      // 33.5 MB (= final output)

    hipLaunchKernelGGL(compute_k_kernel, dim3(128), dim3(256), 0, stream,
                       logA, Aim, Bre, Bim, Cre, Cim, logdt, kbuf);
    hipLaunchKernelGGL(conv2d_kernel, dim3(B_ * C_), dim3(512), 0, stream,
                       u_re, u_im, kbuf, z_re, z_im);
    hipLaunchKernelGGL(mix_kernel, dim3(B_ * 128), dim3(256), 0, stream,
                       z_re, z_im, Wre, Wim);
}